// Round 3
// baseline (4291.474 us; speedup 1.0000x reference)
//
#include <hip/hip_runtime.h>
#include <stdint.h>

#define THREADS 256
#define ITEMS 16
#define CHUNK (THREADS * ITEMS)

// ---------------- threefry2x32, JAX-compatible (20 rounds) ----------------
__host__ __device__ static inline void tf2x32(uint32_t k0, uint32_t k1,
                                              uint32_t x0, uint32_t x1,
                                              uint32_t* o0, uint32_t* o1) {
  uint32_t ks[3] = {k0, k1, k0 ^ k1 ^ 0x1BD11BDAu};
  x0 += ks[0]; x1 += ks[1];
  const uint32_t RA[4] = {13u, 15u, 26u, 6u};
  const uint32_t RB[4] = {17u, 29u, 16u, 24u};
#pragma unroll
  for (int g = 0; g < 5; ++g) {
    const uint32_t* R = (g & 1) ? RB : RA;
#pragma unroll
    for (int j = 0; j < 4; ++j) {
      x0 += x1;
      x1 = (x1 << R[j]) | (x1 >> (32u - R[j]));
      x1 ^= x0;
    }
    x0 += ks[(g + 1) % 3];
    x1 += ks[(g + 2) % 3] + (uint32_t)(g + 1);
  }
  *o0 = x0; *o1 = x1;
}

// jax partitionable random_bits(key, 32, (n,))[i]: block (hi=0, lo=i), xor of outputs
__device__ static inline uint32_t rbits32(uint32_t ka, uint32_t kb, uint32_t i) {
  uint32_t o0, o1;
  tf2x32(ka, kb, 0u, i, &o0, &o1);
  return o0 ^ o1;
}

// ---------------- small utilities ----------------
__device__ static inline uint32_t block_scan_excl(uint32_t v, uint32_t* lds) {
  int t = threadIdx.x;
  lds[t] = v;
  __syncthreads();
#pragma unroll
  for (int d = 1; d < THREADS; d <<= 1) {
    uint32_t add = (t >= d) ? lds[t - d] : 0u;
    __syncthreads();
    lds[t] += add;
    __syncthreads();
  }
  return lds[t] - v;
}

__device__ static inline int row_of(const int* __restrict__ rowptr, int Nn, int i) {
  int lo = 0, hi = Nn;  // rowptr[lo] <= i < rowptr[hi]
  while (hi - lo > 1) {
    int mid = (lo + hi) >> 1;
    if (rowptr[mid] <= i) lo = mid; else hi = mid;
  }
  return lo;
}

// ---------------- phase kernels ----------------
__global__ void k_hist(const int* __restrict__ row, int E, int* __restrict__ counts) {
  int i = blockIdx.x * blockDim.x + threadIdx.x;
  int st = gridDim.x * blockDim.x;
  for (; i < E; i += st) atomicAdd(&counts[row[i]], 1);
}

__global__ void k_sums_int(const int* __restrict__ d, int n, uint32_t* __restrict__ bsums) {
  __shared__ uint32_t lds[THREADS];
  int b = blockIdx.x, t = threadIdx.x;
  int base = b * CHUNK + t * ITEMS;
  uint32_t s = 0;
#pragma unroll
  for (int j = 0; j < ITEMS; ++j) { int i = base + j; if (i < n) s += (uint32_t)d[i]; }
  lds[t] = s; __syncthreads();
  for (int d2 = THREADS / 2; d2 > 0; d2 >>= 1) { if (t < d2) lds[t] += lds[t + d2]; __syncthreads(); }
  if (t == 0) bsums[b] = lds[0];
}

// single-block exclusive scan in place (n <= 65536), optional grand-total out
__global__ void k_scan_single(uint32_t* __restrict__ d, int n, uint32_t* __restrict__ total_out) {
  __shared__ uint32_t lds[THREADS];
  int t = threadIdx.x;
  int K = (n + THREADS - 1) / THREADS;
  int s0 = t * K, s1 = (s0 + K < n) ? (s0 + K) : n;
  uint32_t s = 0;
  for (int j = s0; j < s1; ++j) s += d[j];
  lds[t] = s; __syncthreads();
#pragma unroll
  for (int dd = 1; dd < THREADS; dd <<= 1) {
    uint32_t a = (t >= dd) ? lds[t - dd] : 0u;
    __syncthreads();
    lds[t] += a;
    __syncthreads();
  }
  uint32_t incl = lds[t];
  if (total_out && t == THREADS - 1) *total_out = incl;
  uint32_t run = incl - s;
  for (int j = s0; j < s1; ++j) { uint32_t tmp = d[j]; d[j] = run; run += tmp; }
}

__global__ void k_excl_write(const int* __restrict__ counts, int n,
                             const uint32_t* __restrict__ bsums, int* __restrict__ outp) {
  __shared__ uint32_t lds[THREADS];
  int b = blockIdx.x, t = threadIdx.x;
  int base = b * CHUNK + t * ITEMS;
  uint32_t v[ITEMS]; uint32_t s = 0;
#pragma unroll
  for (int j = 0; j < ITEMS; ++j) { int i = base + j; uint32_t x = (i < n) ? (uint32_t)counts[i] : 0u; v[j] = x; s += x; }
  uint32_t tp = block_scan_excl(s, lds);
  uint32_t run = bsums[b] + tp;
#pragma unroll
  for (int j = 0; j < ITEMS; ++j) { int i = base + j; if (i < n) outp[i] = (int)run; run += v[j]; }
}

__global__ void k_scatter(const int* __restrict__ row, const int* __restrict__ col, int E,
                          const int* __restrict__ rowptr, int* __restrict__ cursor,
                          int* __restrict__ colA) {
  int i = blockIdx.x * blockDim.x + threadIdx.x;
  int st = gridDim.x * blockDim.x;
  for (; i < E; i += st) {
    int r = row[i];
    int p = rowptr[r] + atomicAdd(&cursor[r], 1);
    colA[p] = col[i];
  }
}

__global__ void k_rowsort(const int* __restrict__ rowptr, int n, int* __restrict__ colA) {
  int v = blockIdx.x * blockDim.x + threadIdx.x;
  int st = gridDim.x * blockDim.x;
  for (; v < n; v += st) {
    int s = rowptr[v], e = rowptr[v + 1];
    for (int a = s + 1; a < e; ++a) {
      int key = colA[a];
      int b2 = a - 1;
      while (b2 >= s && colA[b2] > key) { colA[b2 + 1] = colA[b2]; --b2; }
      colA[b2 + 1] = key;
    }
  }
}

__global__ void k_genbits(uint32_t ka, uint32_t kb, int n,
                          uint32_t* __restrict__ keys, int* __restrict__ vals) {
  int i = blockIdx.x * blockDim.x + threadIdx.x;
  int st = gridDim.x * blockDim.x;
  for (; i < n; i += st) {
    keys[i] = rbits32(ka, kb, (uint32_t)i);
    if (vals) vals[i] = i;
  }
}

__global__ void k_rhist(const uint32_t* __restrict__ keys, int n, int shift, int NB,
                        uint32_t* __restrict__ hist) {
  __shared__ uint32_t h[256];
  int b = blockIdx.x, t = threadIdx.x;
  h[t] = 0; __syncthreads();
  int base = b * CHUNK;
  for (int j = t; j < CHUNK; j += THREADS) {
    int i = base + j;
    if (i < n) atomicAdd(&h[(keys[i] >> shift) & 255u], 1u);
  }
  __syncthreads();
  hist[(size_t)t * NB + b] = h[t];
}

// stable LSD radix scatter pass (ballot multisplit for in-block stable ranks)
__global__ void k_rscatter(const uint32_t* __restrict__ kin, const int* __restrict__ vin,
                           uint32_t* __restrict__ kout, int* __restrict__ vout,
                           const uint32_t* __restrict__ hist, int n, int shift, int NB) {
  __shared__ uint32_t offset[256];
  __shared__ unsigned short wcnt[4][256];
  int b = blockIdx.x, t = threadIdx.x;
  offset[t] = hist[(size_t)t * NB + b];
  __syncthreads();
  int lane = t & 63, wid = t >> 6;
  int base = b * CHUNK;
  for (int batch = 0; batch < ITEMS; ++batch) {
    int i = base + batch * THREADS + t;
    bool act = i < n;
    uint32_t key = act ? kin[i] : 0u;
    uint32_t dig = (key >> shift) & 255u;
    wcnt[0][t] = 0; wcnt[1][t] = 0; wcnt[2][t] = 0; wcnt[3][t] = 0;
    __syncthreads();
    unsigned long long peers = __ballot(act);
#pragma unroll
    for (int bit = 0; bit < 8; ++bit) {
      unsigned long long m = __ballot(act && ((dig >> bit) & 1u));
      peers &= ((dig >> bit) & 1u) ? m : ~m;
    }
    uint32_t rankw = 0;
    if (act) {
      unsigned long long lower = peers & ((1ull << lane) - 1ull);
      rankw = (uint32_t)__popcll(lower);
      if (rankw == 0) wcnt[wid][dig] = (unsigned short)__popcll(peers);
    }
    __syncthreads();
    if (act) {
      uint32_t pre = 0;
      for (int wv = 0; wv < wid; ++wv) pre += wcnt[wv][dig];
      uint32_t dst = offset[dig] + pre + rankw;
      kout[dst] = key;
      vout[dst] = vin[i];
    }
    __syncthreads();
    uint32_t add = (uint32_t)wcnt[0][t] + wcnt[1][t] + wcnt[2][t] + wcnt[3][t];
    offset[t] += add;
    __syncthreads();
  }
}

__global__ void k_walk(const int* __restrict__ start, int S,
                       const int* __restrict__ rowptr, const int* __restrict__ colA,
                       uint8_t* __restrict__ hits,
                       uint32_t k0a, uint32_t k0b, uint32_t k1a, uint32_t k1b,
                       uint32_t k2a, uint32_t k2b) {
  int i = blockIdx.x * blockDim.x + threadIdx.x;
  int st = gridDim.x * blockDim.x;
  for (; i < S; i += st) {
    int cur = start[i];
    bool active = true;
    uint32_t ka[3] = {k0a, k1a, k2a};
    uint32_t kb[3] = {k0b, k1b, k2b};
#pragma unroll
    for (int s = 0; s < 3; ++s) {
      int rp = rowptr[cur];
      int d = rowptr[cur + 1] - rp;
      bool act = active && (d > 0);
      if (act) hits[cur] = 1;
      uint32_t bits = rbits32(ka[s], kb[s], (uint32_t)i);
      float u = __uint_as_float((bits >> 9) | 0x3f800000u) - 1.0f;  // jax uniform [0,1)
      int off = (int)floorf(u * (float)d);
      int dm1 = d - 1; if (dm1 < 0) dm1 = 0;
      if (off > dm1) off = dm1;
      if (act) cur = colA[rp + off];
      active = act;
    }
  }
}

__global__ void k_mask_sums(const uint8_t* __restrict__ hits, int E, int Nn,
                            uint32_t* __restrict__ bsums) {
  __shared__ uint32_t lds[THREADS];
  int b = blockIdx.x, t = threadIdx.x;
  int base = b * CHUNK + t * ITEMS;
  uint32_t s = 0;
#pragma unroll
  for (int j = 0; j < ITEMS; ++j) {
    int i = base + j;
    if (i < E) s += (uint32_t)(!(i < Nn && hits[i]));
  }
  lds[t] = s; __syncthreads();
  for (int d2 = THREADS / 2; d2 > 0; d2 >>= 1) { if (t < d2) lds[t] += lds[t + d2]; __syncthreads(); }
  if (t == 0) bsums[b] = lds[0];
}

// writes: M (mask 0/1), B = remaining cols, C/D = masked rows/cols, plus -1 tail fills
__global__ void k_out_bcdm(const uint8_t* __restrict__ hits, int E, int Nn,
                           const uint32_t* __restrict__ bsums, const uint32_t* __restrict__ nkeep_p,
                           const int* __restrict__ rowptr, const int* __restrict__ colA,
                           int* __restrict__ B, int* __restrict__ C, int* __restrict__ D,
                           int* __restrict__ M) {
  __shared__ uint32_t lds[THREADS];
  int b = blockIdx.x, t = threadIdx.x;
  int base = b * CHUNK + t * ITEMS;
  uint32_t keepbit[ITEMS]; uint32_t s = 0;
#pragma unroll
  for (int j = 0; j < ITEMS; ++j) {
    int i = base + j;
    uint32_t k = 0;
    if (i < E) k = (uint32_t)(!(i < Nn && hits[i]));
    keepbit[j] = k; s += k;
  }
  uint32_t tp = block_scan_excl(s, lds);
  uint32_t kr = bsums[b] + tp;
  uint32_t nk = *nkeep_p;
  uint32_t nm = (uint32_t)E - nk;
#pragma unroll
  for (int j = 0; j < ITEMS; ++j) {
    int i = base + j;
    if (i < E) {
      if (keepbit[j]) { B[kr] = colA[i]; ++kr; }
      else { uint32_t mr = (uint32_t)i - kr; C[mr] = row_of(rowptr, Nn, i); D[mr] = colA[i]; }
      M[i] = keepbit[j] ? 1 : 0;
      if ((uint32_t)i >= nk) B[i] = -1;
      if ((uint32_t)i >= nm) { C[i] = -1; D[i] = -1; }
    }
  }
}

// writes A = remaining rows (overwrites the sorted-col staging; reads nothing from A)
__global__ void k_out_a(const uint8_t* __restrict__ hits, int E, int Nn,
                        const uint32_t* __restrict__ bsums, const uint32_t* __restrict__ nkeep_p,
                        const int* __restrict__ rowptr, int* __restrict__ A) {
  __shared__ uint32_t lds[THREADS];
  int b = blockIdx.x, t = threadIdx.x;
  int base = b * CHUNK + t * ITEMS;
  uint32_t keepbit[ITEMS]; uint32_t s = 0;
#pragma unroll
  for (int j = 0; j < ITEMS; ++j) {
    int i = base + j;
    uint32_t k = 0;
    if (i < E) k = (uint32_t)(!(i < Nn && hits[i]));
    keepbit[j] = k; s += k;
  }
  uint32_t tp = block_scan_excl(s, lds);
  uint32_t kr = bsums[b] + tp;
  uint32_t nk = *nkeep_p;
#pragma unroll
  for (int j = 0; j < ITEMS; ++j) {
    int i = base + j;
    if (i < E) {
      if (keepbit[j]) { A[kr] = row_of(rowptr, Nn, i); ++kr; }
      if ((uint32_t)i >= nk) A[i] = -1;
    }
  }
}

// ---------------- launcher ----------------
extern "C" void kernel_launch(void* const* d_in, const int* in_sizes, int n_in,
                              void* d_out, int out_size, void* d_ws, size_t ws_size,
                              hipStream_t stream) {
  const int E = in_sizes[0] / 2;
  const int Nn = 1000000;   // num_nodes (fixed problem)
  const int S = 700000;     // round(0.7*N) * WALKS_PER_NODE
  const int NB_N = (Nn + CHUNK - 1) / CHUNK;  // 245
  const int NB_E = (E + CHUNK - 1) / CHUNK;   // 3907

  const int* row = (const int*)d_in[0];
  const int* col = row + (size_t)E;

  int* out = (int*)d_out;
  int* A = out;                      // final: remaining rows (staging: sorted cols)
  int* B = out + (size_t)E;          // final: remaining cols
  int* C = out + (size_t)2 * E;      // final: masked rows   (staging: perm buffers)
  int* D = out + (size_t)3 * E;      // final: masked cols
  int* M = out + (size_t)4 * E;      // final: edge_mask (0/1)

  // workspace carve (~9.5 MB)
  char* w = (char*)d_ws;
  int* rowptr = (int*)w;      w += (size_t)(Nn + 1) * 4;
  int* cursor = (int*)w;      w += (size_t)Nn * 4;
  uint8_t* hits = (uint8_t*)w; w += Nn;
  w = (char*)(((uintptr_t)w + 255) & ~(uintptr_t)255);
  uint32_t* bsums = (uint32_t*)w; w += (size_t)4096 * 4;
  uint32_t* hist = (uint32_t*)w;  w += (size_t)256 * NB_N * 4;
  uint32_t* scal = (uint32_t*)w;  w += 64;
  if ((size_t)(w - (char*)d_ws) > ws_size) return;  // insufficient scratch: fail visibly

  // perm staging inside C region (4*Nn ints << 2E ints)
  uint32_t* pkA = (uint32_t*)C;
  int*      pvA = C + (size_t)Nn;
  uint32_t* pkB = (uint32_t*)(C + (size_t)2 * Nn);
  int*      pvB = C + (size_t)3 * Nn;

  // ---- host-side key derivation (JAX threefry, partitionable split = fold_in) ----
  struct KK { uint32_t a, b; };
  auto fold = [](KK k, uint32_t j) { KK r; tf2x32(k.a, k.b, 0u, j, &r.a, &r.b); return r; };
  KK base{0u, 42u};                 // jax.random.key(42)
  KK kperm = fold(base, 0u);        // split(key)[0]
  KK kwalk = fold(base, 1u);        // split(key)[1]
  KK keyA  = fold(kperm, 0u);       // _shuffle round-1: key
  KK sub1  = fold(kperm, 1u);       //                   subkey (sort bits 1)
  KK sub2  = fold(keyA, 1u);        // _shuffle round-2 subkey (sort bits 2)
  KK wk0 = fold(kwalk, 0u), wk1 = fold(kwalk, 1u), wk2 = fold(kwalk, 2u);

  // ---- 1) degree histogram + rowptr ----
  hipMemsetAsync(cursor, 0, (size_t)Nn * 4, stream);
  hipMemsetAsync(hits, 0, (size_t)Nn, stream);
  k_hist<<<4096, THREADS, 0, stream>>>(row, E, cursor);
  k_sums_int<<<NB_N, THREADS, 0, stream>>>(cursor, Nn, bsums);
  k_scan_single<<<1, THREADS, 0, stream>>>(bsums, NB_N, (uint32_t*)(rowptr + Nn)); // rowptr[N]=E
  k_excl_write<<<NB_N, THREADS, 0, stream>>>(cursor, Nn, bsums, rowptr);

  // ---- 2) bucket + per-row sort => lexicographically sorted (row,col) pairs ----
  hipMemsetAsync(cursor, 0, (size_t)Nn * 4, stream);
  k_scatter<<<4096, THREADS, 0, stream>>>(row, col, E, rowptr, cursor, A);
  k_rowsort<<<(Nn + THREADS - 1) / THREADS, THREADS, 0, stream>>>(rowptr, Nn, A);

  // ---- 3) jax.random.permutation(kperm, N): 2 rounds of stable sort by random u32 ----
  auto radix4 = [&](uint32_t* kA, int* vA, uint32_t* kB, int* vB) {
    uint32_t* ki = kA; int* vi = vA; uint32_t* ko = kB; int* vo = vB;
    for (int p = 0; p < 4; ++p) {
      int shift = p * 8;
      k_rhist<<<NB_N, THREADS, 0, stream>>>(ki, Nn, shift, NB_N, hist);
      k_scan_single<<<1, THREADS, 0, stream>>>(hist, 256 * NB_N, (uint32_t*)nullptr);
      k_rscatter<<<NB_N, THREADS, 0, stream>>>(ki, vi, ko, vo, hist, Nn, shift, NB_N);
      uint32_t* tk = ki; ki = ko; ko = tk;
      int* tv = vi; vi = vo; vo = tv;
    }
  };
  k_genbits<<<2048, THREADS, 0, stream>>>(sub1.a, sub1.b, Nn, pkA, pvA);
  radix4(pkA, pvA, pkB, pvB);  // ends back in (pkA, pvA)
  k_genbits<<<2048, THREADS, 0, stream>>>(sub2.a, sub2.b, Nn, pkA, (int*)nullptr);
  radix4(pkA, pvA, pkB, pvB);  // final permutation values in pvA

  // ---- 4) random walks: mark hit nodes ----
  k_walk<<<(S + THREADS - 1) / THREADS, THREADS, 0, stream>>>(
      pvA, S, rowptr, A, hits, wk0.a, wk0.b, wk1.a, wk1.b, wk2.a, wk2.b);

  // ---- 5) stable partition + outputs ----
  k_mask_sums<<<NB_E, THREADS, 0, stream>>>(hits, E, Nn, bsums);
  k_scan_single<<<1, THREADS, 0, stream>>>(bsums, NB_E, &scal[0]);  // scal[0] = n_keep
  k_out_bcdm<<<NB_E, THREADS, 0, stream>>>(hits, E, Nn, bsums, &scal[0], rowptr, A, B, C, D, M);
  k_out_a<<<NB_E, THREADS, 0, stream>>>(hits, E, Nn, bsums, &scal[0], rowptr, A);
}

// Round 5
// 1374.767 us; speedup vs baseline: 3.1216x; 3.1216x over previous
//
#include <hip/hip_runtime.h>
#include <stdint.h>

#define THREADS 256
#define ITEMS 16
#define CHUNK (THREADS * ITEMS)
#define COLMASK 0xFFFFFu

// ---------------- threefry2x32, JAX-compatible (20 rounds) ----------------
__host__ __device__ static inline void tf2x32(uint32_t k0, uint32_t k1,
                                              uint32_t x0, uint32_t x1,
                                              uint32_t* o0, uint32_t* o1) {
  uint32_t ks[3] = {k0, k1, k0 ^ k1 ^ 0x1BD11BDAu};
  x0 += ks[0]; x1 += ks[1];
  const uint32_t RA[4] = {13u, 15u, 26u, 6u};
  const uint32_t RB[4] = {17u, 29u, 16u, 24u};
#pragma unroll
  for (int g = 0; g < 5; ++g) {
    const uint32_t* R = (g & 1) ? RB : RA;
#pragma unroll
    for (int j = 0; j < 4; ++j) {
      x0 += x1;
      x1 = (x1 << R[j]) | (x1 >> (32u - R[j]));
      x1 ^= x0;
    }
    x0 += ks[(g + 1) % 3];
    x1 += ks[(g + 2) % 3] + (uint32_t)(g + 1);
  }
  *o0 = x0; *o1 = x1;
}

__device__ static inline uint32_t rbits32(uint32_t ka, uint32_t kb, uint32_t i) {
  uint32_t o0, o1;
  tf2x32(ka, kb, 0u, i, &o0, &o1);
  return o0 ^ o1;
}

// ---------------- block exclusive scan (all threads must call) ----------------
__device__ static inline uint32_t block_scan_excl(uint32_t v, uint32_t* lds) {
  int t = threadIdx.x;
  lds[t] = v;
  __syncthreads();
#pragma unroll
  for (int d = 1; d < THREADS; d <<= 1) {
    uint32_t add = (t >= d) ? lds[t - d] : 0u;
    __syncthreads();
    lds[t] += add;
    __syncthreads();
  }
  return lds[t] - v;
}

// ---------------- hierarchical scan helpers ----------------
__global__ void k_sums_u32(const uint32_t* __restrict__ d, int n, uint32_t* __restrict__ bsums) {
  __shared__ uint32_t lds[THREADS];
  int b = blockIdx.x, t = threadIdx.x;
  int base = b * CHUNK + t * ITEMS;
  uint32_t s = 0;
#pragma unroll
  for (int j = 0; j < ITEMS; ++j) { int i = base + j; if (i < n) s += d[i]; }
  lds[t] = s; __syncthreads();
  for (int d2 = THREADS / 2; d2 > 0; d2 >>= 1) { if (t < d2) lds[t] += lds[t + d2]; __syncthreads(); }
  if (t == 0) bsums[b] = lds[0];
}

// single-block exclusive scan in place (n <= 65536), optional grand-total out
__global__ void k_scan_single(uint32_t* __restrict__ d, int n, uint32_t* __restrict__ total_out) {
  __shared__ uint32_t lds[THREADS];
  int t = threadIdx.x;
  int K = (n + THREADS - 1) / THREADS;
  int s0 = t * K, s1 = (s0 + K < n) ? (s0 + K) : n;
  uint32_t s = 0;
  for (int j = s0; j < s1; ++j) s += d[j];
  lds[t] = s; __syncthreads();
#pragma unroll
  for (int dd = 1; dd < THREADS; dd <<= 1) {
    uint32_t a = (t >= dd) ? lds[t - dd] : 0u;
    __syncthreads();
    lds[t] += a;
    __syncthreads();
  }
  uint32_t incl = lds[t];
  if (total_out && t == THREADS - 1) *total_out = incl;
  uint32_t run = incl - s;
  for (int j = s0; j < s1; ++j) { uint32_t tmp = d[j]; d[j] = run; run += tmp; }
}

__global__ void k_excl_u32(uint32_t* __restrict__ d, int n, const uint32_t* __restrict__ bsums) {
  __shared__ uint32_t lds[THREADS];
  int b = blockIdx.x, t = threadIdx.x;
  int base = b * CHUNK + t * ITEMS;
  uint32_t v[ITEMS]; uint32_t s = 0;
#pragma unroll
  for (int j = 0; j < ITEMS; ++j) { int i = base + j; uint32_t x = (i < n) ? d[i] : 0u; v[j] = x; s += x; }
  uint32_t run = bsums[b] + block_scan_excl(s, lds);
#pragma unroll
  for (int j = 0; j < ITEMS; ++j) { int i = base + j; if (i < n) d[i] = run; run += v[j]; }
}

// ---------------- edge sort: pack + 40-bit LSD radix (u64 keys) ----------------
__global__ void k_pack_hist(const int* __restrict__ row, const int* __restrict__ col, int n,
                            uint64_t* __restrict__ U, int NB, uint32_t* __restrict__ hist) {
  __shared__ uint32_t h[256];
  int b = blockIdx.x, t = threadIdx.x;
  h[t] = 0; __syncthreads();
  int base = b * CHUNK;
  for (int j = t; j < CHUNK; j += THREADS) {
    int i = base + j;
    if (i < n) {
      uint64_t key = ((uint64_t)(uint32_t)row[i] << 20) | (uint32_t)col[i];
      U[i] = key;
      atomicAdd(&h[(uint32_t)key & 255u], 1u);
    }
  }
  __syncthreads();
  hist[(size_t)t * NB + b] = h[t];
}

__global__ void k_rhist64(const uint64_t* __restrict__ keys, int n, int shift, int NB,
                          uint32_t* __restrict__ hist) {
  __shared__ uint32_t h[256];
  int b = blockIdx.x, t = threadIdx.x;
  h[t] = 0; __syncthreads();
  int base = b * CHUNK;
  for (int j = t; j < CHUNK; j += THREADS) {
    int i = base + j;
    if (i < n) atomicAdd(&h[(uint32_t)(keys[i] >> shift) & 255u], 1u);
  }
  __syncthreads();
  hist[(size_t)t * NB + b] = h[t];
}

// Three-phase block radix scatter:
//  P1: stable local rank per key (lcnt accumulation + ballot rank), keys/ranks in regs
//  P2: scan lcnt -> digit bases lst; place keys digit-partitioned into lkeys
//  P3: linear sweep of lkeys -> coalesced digit-run writes to global
__global__ __launch_bounds__(THREADS) void k_rscatter64(
    const uint64_t* __restrict__ kin, uint64_t* __restrict__ kout,
    const uint32_t* __restrict__ hist, int n, int shift, int NB) {
  __shared__ uint64_t lkeys[CHUNK];           // 32 KB
  __shared__ uint32_t lcnt[256];
  __shared__ uint32_t lst[256];
  __shared__ uint32_t gofs[256];
  __shared__ uint32_t stmp[THREADS];
  __shared__ unsigned short wcnt[4][256];
  int b = blockIdx.x, t = threadIdx.x;
  lcnt[t] = 0;
  gofs[t] = hist[(size_t)t * NB + b];
  int lane = t & 63, wid = t >> 6;
  int base = b * CHUNK;
  uint64_t mykey[ITEMS];
  uint32_t myrank[ITEMS];
  __syncthreads();
#pragma unroll
  for (int batch = 0; batch < ITEMS; ++batch) {
    int i = base + batch * THREADS + t;
    bool act = i < n;
    uint64_t key = act ? kin[i] : 0ull;
    mykey[batch] = key;
    uint32_t dig = (uint32_t)(key >> shift) & 255u;
    wcnt[0][t] = 0; wcnt[1][t] = 0; wcnt[2][t] = 0; wcnt[3][t] = 0;
    __syncthreads();
    unsigned long long peers = __ballot(act);
#pragma unroll
    for (int bit = 0; bit < 8; ++bit) {
      unsigned long long m = __ballot(act && ((dig >> bit) & 1u));
      peers &= ((dig >> bit) & 1u) ? m : ~m;
    }
    uint32_t rankw = 0;
    if (act) {
      rankw = (uint32_t)__popcll(peers & ((1ull << lane) - 1ull));
      if (rankw == 0) wcnt[wid][dig] = (unsigned short)__popcll(peers);
    }
    __syncthreads();
    uint32_t pre = 0;
#pragma unroll
    for (int wv = 0; wv < 4; ++wv) if (wv < wid) pre += wcnt[wv][dig];
    myrank[batch] = lcnt[dig] + pre + rankw;   // stable rank within digit, this block
    __syncthreads();
    lcnt[t] += (uint32_t)wcnt[0][t] + wcnt[1][t] + wcnt[2][t] + wcnt[3][t];
    __syncthreads();
  }
  // P2: digit bases within the block
  uint32_t cnt = lcnt[t];
  uint32_t ls = block_scan_excl(cnt, stmp);
  lst[t] = ls;
  __syncthreads();
#pragma unroll
  for (int batch = 0; batch < ITEMS; ++batch) {
    int i = base + batch * THREADS + t;
    if (i < n) {
      uint64_t key = mykey[batch];
      uint32_t dig = (uint32_t)(key >> shift) & 255u;
      lkeys[lst[dig] + myrank[batch]] = key;
    }
  }
  __syncthreads();
  // P3: coalesced write-out (same-digit keys contiguous in lkeys)
  int nloc = n - base; if (nloc > CHUNK) nloc = CHUNK;
  for (int j = t; j < nloc; j += THREADS) {
    uint64_t key = lkeys[j];
    uint32_t dig = (uint32_t)(key >> shift) & 255u;
    kout[gofs[dig] + ((uint32_t)j - lst[dig])] = key;
  }
}

// rowptr[v] = first index i with row(U[i]) >= v; rowptr[Nn] = E
__global__ void k_rowptr(const uint64_t* __restrict__ U, int E, int Nn, int* __restrict__ rowptr) {
  int i = blockIdx.x * blockDim.x + threadIdx.x;
  int st = gridDim.x * blockDim.x;
  for (; i < E; i += st) {
    int r = (int)(U[i] >> 20); if (r > Nn - 1) r = Nn - 1;      // defensive clamp
    int rp;
    if (i == 0) rp = -1;
    else { rp = (int)(U[i - 1] >> 20); if (rp > Nn - 1) rp = Nn - 1; }
    for (int v = rp + 1; v <= r; ++v) rowptr[v] = i;
    if (i == E - 1) { for (int v = r + 1; v <= Nn; ++v) rowptr[v] = E; }
  }
}

// ---------------- permutation (1M u32 keys + payload), stable LSD radix ----------------
__global__ void k_genbits(uint32_t ka, uint32_t kb, int n,
                          uint32_t* __restrict__ keys, int* __restrict__ vals) {
  int i = blockIdx.x * blockDim.x + threadIdx.x;
  int st = gridDim.x * blockDim.x;
  for (; i < n; i += st) {
    keys[i] = rbits32(ka, kb, (uint32_t)i);
    if (vals) vals[i] = i;
  }
}

__global__ void k_rhist(const uint32_t* __restrict__ keys, int n, int shift, int NB,
                        uint32_t* __restrict__ hist) {
  __shared__ uint32_t h[256];
  int b = blockIdx.x, t = threadIdx.x;
  h[t] = 0; __syncthreads();
  int base = b * CHUNK;
  for (int j = t; j < CHUNK; j += THREADS) {
    int i = base + j;
    if (i < n) atomicAdd(&h[(keys[i] >> shift) & 255u], 1u);
  }
  __syncthreads();
  hist[(size_t)t * NB + b] = h[t];
}

__global__ void k_rscatter(const uint32_t* __restrict__ kin, const int* __restrict__ vin,
                           uint32_t* __restrict__ kout, int* __restrict__ vout,
                           const uint32_t* __restrict__ hist, int n, int shift, int NB) {
  __shared__ uint32_t offset[256];
  __shared__ unsigned short wcnt[4][256];
  int b = blockIdx.x, t = threadIdx.x;
  offset[t] = hist[(size_t)t * NB + b];
  __syncthreads();
  int lane = t & 63, wid = t >> 6;
  int base = b * CHUNK;
  for (int batch = 0; batch < ITEMS; ++batch) {
    int i = base + batch * THREADS + t;
    bool act = i < n;
    uint32_t key = act ? kin[i] : 0u;
    uint32_t dig = (key >> shift) & 255u;
    wcnt[0][t] = 0; wcnt[1][t] = 0; wcnt[2][t] = 0; wcnt[3][t] = 0;
    __syncthreads();
    unsigned long long peers = __ballot(act);
#pragma unroll
    for (int bit = 0; bit < 8; ++bit) {
      unsigned long long m = __ballot(act && ((dig >> bit) & 1u));
      peers &= ((dig >> bit) & 1u) ? m : ~m;
    }
    uint32_t rankw = 0;
    if (act) {
      rankw = (uint32_t)__popcll(peers & ((1ull << lane) - 1ull));
      if (rankw == 0) wcnt[wid][dig] = (unsigned short)__popcll(peers);
    }
    __syncthreads();
    if (act) {
      uint32_t pre = 0;
      for (int wv = 0; wv < wid; ++wv) pre += wcnt[wv][dig];
      uint32_t dst = offset[dig] + pre + rankw;
      kout[dst] = key;
      vout[dst] = vin[i];
    }
    __syncthreads();
    offset[t] += (uint32_t)wcnt[0][t] + wcnt[1][t] + wcnt[2][t] + wcnt[3][t];
    __syncthreads();
  }
}

// ---------------- random walks ----------------
__global__ void k_walk(const int* __restrict__ start, int S,
                       const int* __restrict__ rowptr, const uint64_t* __restrict__ U,
                       uint8_t* __restrict__ hits,
                       uint32_t k0a, uint32_t k0b, uint32_t k1a, uint32_t k1b,
                       uint32_t k2a, uint32_t k2b) {
  int i = blockIdx.x * blockDim.x + threadIdx.x;
  int st = gridDim.x * blockDim.x;
  for (; i < S; i += st) {
    int cur = start[i];
    bool active = true;
    uint32_t ka[3] = {k0a, k1a, k2a};
    uint32_t kb[3] = {k0b, k1b, k2b};
#pragma unroll
    for (int s = 0; s < 3; ++s) {
      int rp = rowptr[cur];
      int d = rowptr[cur + 1] - rp;
      bool act = active && (d > 0);
      if (act) hits[cur] = 1;
      uint32_t bits = rbits32(ka[s], kb[s], (uint32_t)i);
      float u = __uint_as_float((bits >> 9) | 0x3f800000u) - 1.0f;  // jax uniform [0,1)
      int off = (int)floorf(u * (float)d);
      int dm1 = d - 1; if (dm1 < 0) dm1 = 0;
      if (off > dm1) off = dm1;
      if (act) cur = (int)(U[rp + off] & COLMASK);
      active = act;
    }
  }
}

// ---------------- outputs (masked edges only exist at i < Nn) ----------------
__global__ void k_mask_sums(const uint8_t* __restrict__ hits, int E, int Nn,
                            uint32_t* __restrict__ bsums) {
  __shared__ uint32_t lds[THREADS];
  int b = blockIdx.x, t = threadIdx.x;
  int base = b * CHUNK + t * ITEMS;
  uint32_t s = 0;
#pragma unroll
  for (int j = 0; j < ITEMS; ++j) {
    int i = base + j;
    if (i < E) s += (uint32_t)(!(i < Nn && hits[i]));
  }
  lds[t] = s; __syncthreads();
  for (int d2 = THREADS / 2; d2 > 0; d2 >>= 1) { if (t < d2) lds[t] += lds[t + d2]; __syncthreads(); }
  if (t == 0) bsums[b] = lds[0];
}

// head pass i<Nn: keeps -> A/B, masked -> mstage, M written
__global__ void k_out_head(const uint64_t* __restrict__ U, const uint8_t* __restrict__ hits,
                           int Nn, const uint32_t* __restrict__ bsums,
                           int* __restrict__ A, int* __restrict__ B, int* __restrict__ M,
                           uint64_t* __restrict__ mstage) {
  __shared__ uint32_t lds[THREADS];
  int b = blockIdx.x, t = threadIdx.x;
  int base = b * CHUNK + t * ITEMS;
  uint32_t keep[ITEMS]; uint32_t s = 0;
#pragma unroll
  for (int j = 0; j < ITEMS; ++j) {
    int i = base + j;
    uint32_t k = (i < Nn) ? (uint32_t)(!hits[i]) : 0u;
    keep[j] = k; s += k;
  }
  uint32_t kr = bsums[b] + block_scan_excl(s, lds);
#pragma unroll
  for (int j = 0; j < ITEMS; ++j) {
    int i = base + j;
    if (i < Nn) {
      uint64_t key = U[i];
      if (keep[j]) { A[kr] = (int)(key >> 20); B[kr] = (int)(key & COLMASK); M[i] = 1; ++kr; }
      else { uint32_t mr = (uint32_t)i - kr; mstage[mr] = key; M[i] = 0; }
    }
  }
}

// tail pass i>=Nn: pure shift-by-nm copy (all keeps)
__global__ void k_out_tail(const uint64_t* __restrict__ U, int E, int Nn,
                           const uint32_t* __restrict__ keephead,
                           int* __restrict__ A, int* __restrict__ B, int* __restrict__ M) {
  int nm = Nn - (int)*keephead;
  int i = Nn + blockIdx.x * blockDim.x + threadIdx.x;
  int st = gridDim.x * blockDim.x;
  for (; i < E; i += st) {
    uint64_t key = U[i];
    A[i - nm] = (int)(key >> 20);
    B[i - nm] = (int)(key & COLMASK);
    M[i] = 1;
  }
}

// final: fill C/D from mstage (+ -1 tails), and -1 tails of A/B. Overwrites dead U1.
__global__ void k_out_cd(const uint64_t* __restrict__ mstage, int E, int Nn,
                         const uint32_t* __restrict__ keephead,
                         int* __restrict__ A, int* __restrict__ B,
                         int* __restrict__ C, int* __restrict__ D) {
  int nm = Nn - (int)*keephead;
  int j = blockIdx.x * blockDim.x + threadIdx.x;
  int st = gridDim.x * blockDim.x;
  for (; j < E; j += st) {
    if (j < nm) { uint64_t k = mstage[j]; C[j] = (int)(k >> 20); D[j] = (int)(k & COLMASK); }
    else { C[j] = -1; D[j] = -1; }
    if (j >= E - nm) { A[j] = -1; B[j] = -1; }
  }
}

// ---------------- launcher ----------------
extern "C" void kernel_launch(void* const* d_in, const int* in_sizes, int n_in,
                              void* d_out, int out_size, void* d_ws, size_t ws_size,
                              hipStream_t stream) {
  const int E = in_sizes[0] / 2;
  const int Nn = 1000000;   // num_nodes (fixed problem)
  const int S = 700000;     // round(0.7*N) * WALKS_PER_NODE
  const int NB_N = (Nn + CHUNK - 1) / CHUNK;  // 245
  const int NB_E = (E + CHUNK - 1) / CHUNK;   // 3907
  const int HN = 256 * NB_E;                  // edge hist entries (1,000,192)

  const int* row = (const int*)d_in[0];
  const int* col = row + (size_t)E;

  int* out = (int*)d_out;
  int* A = out;                      // final: remaining rows
  int* B = out + (size_t)E;          // final: remaining cols
  int* C = out + (size_t)2 * E;      // final: masked rows
  int* D = out + (size_t)3 * E;      // final: masked cols
  int* M = out + (size_t)4 * E;      // final: edge_mask (0/1); staging: perm buffers
  uint64_t* U0 = (uint64_t*)out;                    // spans A+B (128MB)
  uint64_t* U1 = (uint64_t*)(out + (size_t)2 * E);  // spans C+D (128MB)

  // workspace carve (~9.0 MB)
  char* w = (char*)d_ws;
  int* rowptr = (int*)w;          w += (size_t)(Nn + 1) * 4;   // dead after walk
  uint32_t* ehist = (uint32_t*)w; w += (size_t)HN * 4;         // dead after sorts
  uint8_t* hits = (uint8_t*)w;    w += Nn;
  w = (char*)(((uintptr_t)w + 255) & ~(uintptr_t)255);
  uint32_t* bsums = (uint32_t*)w; w += (size_t)4096 * 4;
  uint32_t* scal = (uint32_t*)w;  w += 64;
  if ((size_t)(w - (char*)d_ws) > ws_size) return;  // insufficient scratch: fail visibly
  // masked-pair staging (<= Nn u64 = 8MB) aliases rowptr+ehist (8,000,772 B), used only after walk
  uint64_t* mstage = (uint64_t*)d_ws;

  // perm staging in M region (4*Nn ints = 16MB << 64MB); dead before M is written
  uint32_t* pkA = (uint32_t*)M;
  int*      pvA = M + (size_t)Nn;
  uint32_t* pkB = (uint32_t*)(M + (size_t)2 * Nn);
  int*      pvB = M + (size_t)3 * Nn;

  // ---- host-side key derivation (JAX threefry, partitionable split = fold_in) ----
  struct KK { uint32_t a, b; };
  auto fold = [](KK k, uint32_t j) { KK r; tf2x32(k.a, k.b, 0u, j, &r.a, &r.b); return r; };
  KK base{0u, 42u};
  KK kperm = fold(base, 0u);
  KK kwalk = fold(base, 1u);
  KK keyA  = fold(kperm, 0u);
  KK sub1  = fold(kperm, 1u);
  KK sub2  = fold(keyA, 1u);
  KK wk0 = fold(kwalk, 0u), wk1 = fold(kwalk, 1u), wk2 = fold(kwalk, 2u);

  auto scan_u32 = [&](uint32_t* d, int n, uint32_t* total) {
    int SB = (n + CHUNK - 1) / CHUNK;
    k_sums_u32<<<SB, THREADS, 0, stream>>>(d, n, bsums);
    k_scan_single<<<1, THREADS, 0, stream>>>(bsums, SB, total);
    k_excl_u32<<<SB, THREADS, 0, stream>>>(d, n, bsums);
  };

  hipMemsetAsync(hits, 0, (size_t)Nn, stream);

  // ---- 1) pack (row<<20|col) + first-pass histogram ----
  k_pack_hist<<<NB_E, THREADS, 0, stream>>>(row, col, E, U0, NB_E, ehist);

  // ---- 2) 40-bit LSD radix sort, 5 x 8-bit passes; U0 -> ... -> U1 ----
  {
    uint64_t* ki = U0; uint64_t* ko = U1;
    for (int p = 0; p < 5; ++p) {
      int shift = 8 * p;
      if (p > 0) k_rhist64<<<NB_E, THREADS, 0, stream>>>(ki, E, shift, NB_E, ehist);
      scan_u32(ehist, HN, nullptr);
      k_rscatter64<<<NB_E, THREADS, 0, stream>>>(ki, ko, ehist, E, shift, NB_E);
      uint64_t* tmp = ki; ki = ko; ko = tmp;
    }
    // sorted keys now in U1 (C+D region)
  }

  // ---- 3) rowptr from sorted keys ----
  k_rowptr<<<4096, THREADS, 0, stream>>>(U1, E, Nn, rowptr);

  // ---- 4) jax.random.permutation(kperm, N): 2 rounds of stable sort by random u32 ----
  auto radix4 = [&](uint32_t* kA, int* vA, uint32_t* kB, int* vB) {
    uint32_t* ki = kA; int* vi = vA; uint32_t* ko = kB; int* vo = vB;
    for (int p = 0; p < 4; ++p) {
      int shift = p * 8;
      k_rhist<<<NB_N, THREADS, 0, stream>>>(ki, Nn, shift, NB_N, ehist);
      scan_u32(ehist, 256 * NB_N, nullptr);
      k_rscatter<<<NB_N, THREADS, 0, stream>>>(ki, vi, ko, vo, ehist, Nn, shift, NB_N);
      uint32_t* tk = ki; ki = ko; ko = tk;
      int* tv = vi; vi = vo; vo = tv;
    }
  };
  k_genbits<<<2048, THREADS, 0, stream>>>(sub1.a, sub1.b, Nn, pkA, pvA);
  radix4(pkA, pvA, pkB, pvB);
  k_genbits<<<2048, THREADS, 0, stream>>>(sub2.a, sub2.b, Nn, pkA, (int*)nullptr);
  radix4(pkA, pvA, pkB, pvB);  // final permutation values in pvA

  // ---- 5) random walks: mark hit nodes ----
  k_walk<<<(S + THREADS - 1) / THREADS, THREADS, 0, stream>>>(
      pvA, S, rowptr, U1, hits, wk0.a, wk0.b, wk1.a, wk1.b, wk2.a, wk2.b);

  // ---- 6) outputs: head compaction (i<Nn), tail shift-copy, C/D fill ----
  k_mask_sums<<<NB_N, THREADS, 0, stream>>>(hits, Nn, Nn, bsums);
  k_scan_single<<<1, THREADS, 0, stream>>>(bsums, NB_N, &scal[0]);  // scal[0] = keeps among i<Nn
  k_out_head<<<NB_N, THREADS, 0, stream>>>(U1, hits, Nn, bsums, A, B, M, mstage);
  k_out_tail<<<4096, THREADS, 0, stream>>>(U1, E, Nn, &scal[0], A, B, M);
  k_out_cd<<<4096, THREADS, 0, stream>>>(mstage, E, Nn, &scal[0], A, B, C, D);
}